// Round 6
// baseline (212.760 us; speedup 1.0000x reference)
//
#include <hip/hip_runtime.h>
#include <stdint.h>

// ---------------------------------------------------------------------------
// CausalSelfAttention fused pipeline for MI355X (gfx950)
//   B=4, T=2048, C=1024, H=16, hd=64
// Round 6: k_gemm — counted-vmcnt double-buffered K-loop (round-5 attn
//          pattern: stage t+1, s_waitcnt vmcnt(4), raw barriers, loads in
//          flight across barriers). k_attn — T13 defer-max (skip O-rescale
//          when per-tile max grows <= 8 in log2 domain).
// ---------------------------------------------------------------------------

typedef __bf16 bf16x8 __attribute__((ext_vector_type(8)));
typedef float f32x4 __attribute__((ext_vector_type(4)));
typedef unsigned short u16x8 __attribute__((ext_vector_type(8)));

#define DEVINL static __device__ __forceinline__

DEVINL unsigned short f2b(float f) {
  __bf16 h = (__bf16)f;           // RNE
  return __builtin_bit_cast(unsigned short, h);
}

DEVINL void gld16(const void* g, void* l) {
  __builtin_amdgcn_global_load_lds(
      (const __attribute__((address_space(1))) void*)g,
      (__attribute__((address_space(3))) void*)l, 16, 0, 0);
}

DEVINL f32x4 mfma16(bf16x8 a, bf16x8 b, f32x4 c) {
  return __builtin_amdgcn_mfma_f32_16x16x32_bf16(a, b, c, 0, 0, 0);
}

#define SCHED_FENCE() __builtin_amdgcn_sched_barrier(0)

// ---------------------------------------------------------------- cast x->bf16
__global__ __launch_bounds__(256) void k_cast_bf16(const float* __restrict__ in,
                                                   unsigned short* __restrict__ out,
                                                   int n8) {
  int i = blockIdx.x * 256 + threadIdx.x;
  if (i >= n8) return;
  const float4* p = (const float4*)in + (size_t)i * 2;
  float4 a = p[0], b = p[1];
  u16x8 o;
  o[0] = f2b(a.x); o[1] = f2b(a.y); o[2] = f2b(a.z); o[3] = f2b(a.w);
  o[4] = f2b(b.x); o[5] = f2b(b.y); o[6] = f2b(b.z); o[7] = f2b(b.w);
  *(u16x8*)(out + (size_t)i * 8) = o;
}

// ------------------------------------------- W [R][C] f32 -> Wt [C][R] bf16
__global__ __launch_bounds__(256) void k_transpose_w(const float* __restrict__ in,
                                                     unsigned short* __restrict__ out,
                                                     int R, int C) {
  __shared__ float t[64][65];
  int ci = blockIdx.x * 64, ri = blockIdx.y * 64;
  int tid = threadIdx.x;
#pragma unroll
  for (int j = 0; j < 4; ++j) {
    int c = tid + j * 256;           // 0..1023 float4 chunks of the 64x64 tile
    int row = c >> 4;
    int col = (c & 15) * 4;
    float4 v = *(const float4*)(in + (size_t)(ri + row) * C + ci + col);
    t[row][col] = v.x; t[row][col + 1] = v.y; t[row][col + 2] = v.z; t[row][col + 3] = v.w;
  }
  __syncthreads();
  int cc = tid >> 2;                 // output row (C index), 0..63
  int seg = (tid & 3) * 16;
  u16x8 o0, o1;
#pragma unroll
  for (int j = 0; j < 8; ++j) o0[j] = f2b(t[seg + j][cc]);
#pragma unroll
  for (int j = 0; j < 8; ++j) o1[j] = f2b(t[seg + 8 + j][cc]);
  unsigned short* dst = out + (size_t)(ci + cc) * R + ri + seg;
  *(u16x8*)dst = o0;
  *(u16x8*)(dst + 8) = o1;
}

// --------------------------------- V [bh][2048][64] -> Vt [bh][64][2048] bf16
__global__ __launch_bounds__(256) void k_transpose_v(const unsigned short* __restrict__ v,
                                                     unsigned short* __restrict__ vt) {
  __shared__ unsigned short s[64][65];
  int bh = blockIdx.y;
  int t0 = blockIdx.x * 64;
  int tid = threadIdx.x;
  const unsigned short* src = v + ((size_t)bh * 2048 + t0) * 64;
#pragma unroll
  for (int j = 0; j < 2; ++j) {
    int c = tid + j * 256;           // 0..511 (16B chunks of 64x64 bf16 tile)
    int row = c >> 3;
    int col = (c & 7) * 8;
    u16x8 x = *(const u16x8*)(src + (size_t)row * 64 + col);
#pragma unroll
    for (int q = 0; q < 8; ++q) s[row][col + q] = x[q];
  }
  __syncthreads();
  int d = tid >> 2;                  // 0..63
  int seg = (tid & 3) * 16;
  u16x8 o0, o1;
#pragma unroll
  for (int j = 0; j < 8; ++j) o0[j] = s[seg + j][d];
#pragma unroll
  for (int j = 0; j < 8; ++j) o1[j] = s[seg + 8 + j][d];
  unsigned short* dst = vt + ((size_t)bh * 64 + d) * 2048 + t0 + seg;
  *(u16x8*)dst = o0;
  *(u16x8*)(dst + 8) = o1;
}

// ---------------------------------------------------------------- GEMM (A Bt)
// A [M][K] bf16, Bt [N][K] bf16. 128x128 tile, BK=32, 4 waves (2x2 of 64x64).
// Double-buffered LDS with counted vmcnt: stage K-step t+1, wait vmcnt(4)
// (the 4 loads for step t), raw barriers; vmcnt(0) only on the last step.
// MODE 0: scatter into q/k/v per-head layout (q scaled). MODE 1: fp32 C out.
template <int MODE>
__global__ __launch_bounds__(256) void k_gemm(const unsigned short* __restrict__ A,
                                              const unsigned short* __restrict__ Bt,
                                              int M, int N, int K,
                                              float* __restrict__ Cf,
                                              unsigned short* __restrict__ qo,
                                              unsigned short* __restrict__ ko,
                                              unsigned short* __restrict__ vo,
                                              float qscale) {
  __shared__ unsigned short As[2][128 * 32];   // 16 KB
  __shared__ unsigned short Bs[2][128 * 32];   // 16 KB
  int tid = threadIdx.x;
  int w = tid >> 6, lane = tid & 63, l15 = lane & 15, l4 = lane >> 4;
  int bn = blockIdx.x, bm = blockIdx.y;
  int wr = (w >> 1) * 64, wc = (w & 1) * 64;
  f32x4 acc[4][4];
#pragma unroll
  for (int i = 0; i < 4; ++i)
#pragma unroll
    for (int j = 0; j < 4; ++j) acc[i][j] = (f32x4){0.f, 0.f, 0.f, 0.f};
  const char* Ab = (const char*)(A + (size_t)bm * 128 * K);
  const char* Bb = (const char*)(Bt + (size_t)bn * 128 * K);
  // per-thread staging chunks (4 gld16 per K-step)
  int c_0 = tid, c_1 = tid + 256;
  int row0 = c_0 >> 2, cb0 = (c_0 & 3) * 16;
  int row1 = c_1 >> 2, cb1 = (c_1 & 3) * 16;

  auto stage = [&](int kt, int buf) {
    gld16(Ab + ((size_t)row0 * K + kt) * 2 + cb0, (char*)As[buf] + c_0 * 16);
    gld16(Bb + ((size_t)row0 * K + kt) * 2 + cb0, (char*)Bs[buf] + c_0 * 16);
    gld16(Ab + ((size_t)row1 * K + kt) * 2 + cb1, (char*)As[buf] + c_1 * 16);
    gld16(Bb + ((size_t)row1 * K + kt) * 2 + cb1, (char*)Bs[buf] + c_1 * 16);
  };

  const int nkt = K >> 5;
  stage(0, 0);
  SCHED_FENCE();
  for (int t = 0; t < nkt; ++t) {
    int cur = t & 1;
    if (t) {                           // WAR: all waves done reading buf[cur^1]
      SCHED_FENCE();
      __builtin_amdgcn_s_barrier();
      SCHED_FENCE();
    }
    if (t + 1 < nkt) {
      stage((t + 1) * 32, cur ^ 1);
      SCHED_FENCE();
      asm volatile("s_waitcnt vmcnt(4)" ::: "memory");  // step t's loads done
    } else {
      SCHED_FENCE();
      asm volatile("s_waitcnt vmcnt(0)" ::: "memory");
    }
    SCHED_FENCE();
    __builtin_amdgcn_s_barrier();      // RAW: buf[cur] ready for all waves
    SCHED_FENCE();
    const char* Ac = (const char*)As[cur];
    const char* Bc = (const char*)Bs[cur];
    bf16x8 af[4], bfr[4];
#pragma unroll
    for (int m = 0; m < 4; ++m)
      af[m] = *(const bf16x8*)(Ac + (wr + m * 16 + l15) * 64 + l4 * 16);
#pragma unroll
    for (int n = 0; n < 4; ++n)
      bfr[n] = *(const bf16x8*)(Bc + (wc + n * 16 + l15) * 64 + l4 * 16);
    __builtin_amdgcn_s_setprio(1);
#pragma unroll
    for (int m = 0; m < 4; ++m)
#pragma unroll
      for (int n = 0; n < 4; ++n)
        acc[m][n] = mfma16(af[m], bfr[n], acc[m][n]);
    __builtin_amdgcn_s_setprio(0);
  }
  // epilogue: D col = lane&15, row = (lane>>4)*4 + reg  [m89-verified]
#pragma unroll
  for (int m = 0; m < 4; ++m) {
    int grow0 = bm * 128 + wr + m * 16 + l4 * 4;
#pragma unroll
    for (int n = 0; n < 4; ++n) {
      int gcol = bn * 128 + wc + n * 16 + l15;
#pragma unroll
      for (int r = 0; r < 4; ++r) {
        int grow = grow0 + r;
        float val = acc[m][n][r];
        if (MODE == 1) {
          Cf[(size_t)grow * N + gcol] = val;
        } else {
          int which = gcol >> 10, rem = gcol & 1023;
          int h = rem >> 6, d = rem & 63;
          int b = grow >> 11, t = grow & 2047;
          size_t off = (((size_t)(b * 16 + h)) * 2048 + t) * 64 + d;
          if (which == 0)      qo[off] = f2b(val * qscale);
          else if (which == 1) ko[off] = f2b(val);
          else                 vo[off] = f2b(val);
        }
      }
    }
  }
}

// ------------------------------------------------------------ flash attention
// Q,K: [bh][2048][64] bf16 (Q pre-scaled by 0.125*log2e); Vt: [bh][64][2048].
// 4 waves x 16 q-rows per q-tile; each block runs TWO q-tiles (31-p then p)
// -> uniform 33 KV-tiles per block. K/V double-buffered in LDS; counted
// s_waitcnt vmcnt(4) + raw s_barrier. T13 defer-max: skip O-rescale while
// per-tile max grows <= 8 (log2 domain; P bounded by 2^8, bf16-safe).
__global__ __launch_bounds__(256) void k_attn(const unsigned short* __restrict__ Q,
                                              const unsigned short* __restrict__ Kt,
                                              const unsigned short* __restrict__ Vt,
                                              unsigned short* __restrict__ AO) {
  __shared__ unsigned short Ks[2][4096];   // 16 KB  [64 kv][64 d]
  __shared__ unsigned short Vs[2][4096];   // 16 KB  [64 d][64 kv]
  __shared__ unsigned short Ps[4096];      //  8 KB  4 waves x [16 q][64 kv]
  int tid = threadIdx.x;
  int w = tid >> 6, lane = tid & 63, l15 = lane & 15, l4 = lane >> 4;
  // XCD-pinned mapping (perf heuristic): 8 heads per XCD -> 4MB KV per L2.
  int lin = blockIdx.x;
  int xcd = lin & 7, jj = lin >> 3;
  int bh = xcd * 8 + (jj & 7);
  int p = jj >> 3;                       // 0..15: q-tile pair (31-p, p)
  const char* Kb = (const char*)(Kt + (size_t)bh * 2048 * 64);
  const char* Vb = (const char*)(Vt + (size_t)bh * 64 * 2048);
  const int swp = (l15 & 7) << 4;        // P-row swizzle for this lane
  char* Pw = (char*)Ps + w * 2048;
  int b = bh >> 4, h = bh & 15;

  // per-lane staging addresses (2 slices per wave), both-sides swizzle
  int Lb0 = (w * 64 + lane) * 16;
  int Lb1 = ((w + 4) * 64 + lane) * 16;
  int Nb0 = Lb0 ^ (((Lb0 >> 7) & 7) << 4);
  int Nb1 = Lb1 ^ (((Lb1 >> 7) & 7) << 4);
  int d0 = Nb0 >> 7, in0 = Nb0 & 127;
  int d1 = Nb1 >> 7, in1 = Nb1 & 127;

  auto stage = [&](int t, int buf) {
    size_t kv0 = (size_t)t * 64;
    gld16(Kb + kv0 * 128 + Nb0, (char*)Ks[buf] + Lb0);
    gld16(Vb + (size_t)d0 * 4096 + kv0 * 2 + in0, (char*)Vs[buf] + Lb0);
    gld16(Kb + kv0 * 128 + Nb1, (char*)Ks[buf] + Lb1);
    gld16(Vb + (size_t)d1 * 4096 + kv0 * 2 + in1, (char*)Vs[buf] + Lb1);
  };

  auto run = [&](int qi) {
    int q0 = qi * 64;
    const unsigned short* Qb = Q + ((size_t)bh * 2048 + q0 + w * 16) * 64;
    bf16x8 qf0 = *(const bf16x8*)((const char*)Qb + l15 * 128 + l4 * 16);
    bf16x8 qf1 = *(const bf16x8*)((const char*)Qb + l15 * 128 + 64 + l4 * 16);
    f32x4 o[4];
#pragma unroll
    for (int i = 0; i < 4; ++i) o[i] = (f32x4){0.f, 0.f, 0.f, 0.f};
    float mrow = -1e30f, lrow = 0.f;     // per-lane state for q = l15
    const int ntiles = qi + 1;
    const int qg = w * 16 + l15;
    // WAR barrier vs previous run's reads, then stage tile 0 into buf 0
    SCHED_FENCE();
    __builtin_amdgcn_s_barrier();
    SCHED_FENCE();
    stage(0, 0);
    SCHED_FENCE();
    for (int it = 0; it < ntiles; ++it) {
      int cur = it & 1;
      if (it) {                          // WAR: all waves done reading buf[cur^1]
        SCHED_FENCE();
        __builtin_amdgcn_s_barrier();
        SCHED_FENCE();
      }
      if (it + 1 < ntiles) {
        stage(it + 1, cur ^ 1);
        SCHED_FENCE();
        asm volatile("s_waitcnt vmcnt(4)" ::: "memory");  // tile it complete
      } else {
        SCHED_FENCE();
        asm volatile("s_waitcnt vmcnt(0)" ::: "memory");  // last tile: drain
      }
      SCHED_FENCE();
      __builtin_amdgcn_s_barrier();      // RAW: buf[cur] ready for all waves
      SCHED_FENCE();
      const char* Kc = (const char*)Ks[cur];
      const char* Vc = (const char*)Vs[cur];
      // S^T = K Q^T: lane holds s[c][r] = S[q=l15][kv=c*16+l4*4+r]
      f32x4 s[4];
      __builtin_amdgcn_s_setprio(1);
#pragma unroll
      for (int c = 0; c < 4; ++c) {
        int row = c * 16 + l15;
        int base = row * 128 + l4 * 16;
        int sw = (row & 7) << 4;
        bf16x8 k0 = *(const bf16x8*)(Kc + (base ^ sw));
        bf16x8 k1 = *(const bf16x8*)(Kc + ((base + 64) ^ sw));
        f32x4 t = mfma16(k0, qf0, (f32x4){0.f, 0.f, 0.f, 0.f});
        s[c] = mfma16(k1, qf1, t);
      }
      __builtin_amdgcn_s_setprio(0);
      if (it == ntiles - 1) {            // diagonal tile: causal mask
#pragma unroll
        for (int c = 0; c < 4; ++c) {
          int kvb = c * 16 + l4 * 4;
#pragma unroll
          for (int r = 0; r < 4; ++r)
            if (kvb + r > qg) s[c][r] = -1e30f;
        }
      }
      // online softmax: lane-local 16 + 2 shuffles
      float mx = fmaxf(fmaxf(fmaxf(s[0][0], s[0][1]), fmaxf(s[0][2], s[0][3])),
                       fmaxf(fmaxf(s[1][0], s[1][1]), fmaxf(s[1][2], s[1][3])));
      mx = fmaxf(mx, fmaxf(fmaxf(fmaxf(s[2][0], s[2][1]), fmaxf(s[2][2], s[2][3])),
                           fmaxf(fmaxf(s[3][0], s[3][1]), fmaxf(s[3][2], s[3][3]))));
      mx = fmaxf(mx, __shfl_xor(mx, 16));
      mx = fmaxf(mx, __shfl_xor(mx, 32));
      // T13 defer-max: only rescale when max grew by > 8 (wave-uniform)
      if (!__all(mx - mrow <= 8.f)) {
        float mn = fmaxf(mrow, mx);
        float corr = __builtin_amdgcn_exp2f(mrow - mn);
        mrow = mn;
        lrow *= corr;
        float corr_r[4];
#pragma unroll
        for (int r = 0; r < 4; ++r) corr_r[r] = __shfl(corr, l4 * 4 + r);
#pragma unroll
        for (int dc = 0; dc < 4; ++dc)
#pragma unroll
          for (int r = 0; r < 4; ++r) o[dc][r] *= corr_r[r];
      }
      float rs = 0.f;
#pragma unroll
      for (int c = 0; c < 4; ++c) {
        float p0 = __builtin_amdgcn_exp2f(s[c][0] - mrow);
        float p1 = __builtin_amdgcn_exp2f(s[c][1] - mrow);
        float p2 = __builtin_amdgcn_exp2f(s[c][2] - mrow);
        float p3 = __builtin_amdgcn_exp2f(s[c][3] - mrow);
        rs += (p0 + p1) + (p2 + p3);
        uint32_t lo = (uint32_t)f2b(p0) | ((uint32_t)f2b(p1) << 16);
        uint32_t hi = (uint32_t)f2b(p2) | ((uint32_t)f2b(p3) << 16);
        *(uint2*)(Pw + ((l15 * 128 + c * 32 + l4 * 8) ^ swp)) = make_uint2(lo, hi);
      }
      rs += __shfl_xor(rs, 16);
      rs += __shfl_xor(rs, 32);
      lrow += rs;
      // O += P V
      bf16x8 pa[2];
#pragma unroll
      for (int kc = 0; kc < 2; ++kc)
        pa[kc] = *(const bf16x8*)(Pw + ((l15 * 128 + kc * 64 + l4 * 16) ^ swp));
      __builtin_amdgcn_s_setprio(1);
#pragma unroll
      for (int dc = 0; dc < 4; ++dc) {
#pragma unroll
        for (int kc = 0; kc < 2; ++kc) {
          int vrow = dc * 16 + l15;
          int vnat = vrow * 128 + kc * 64 + l4 * 16;
          bf16x8 vb = *(const bf16x8*)(Vc + (vnat ^ ((vrow & 7) << 4)));
          o[dc] = mfma16(pa[kc], vb, o[dc]);
        }
      }
      __builtin_amdgcn_s_setprio(0);
    }
    float inv[4];
#pragma unroll
    for (int r = 0; r < 4; ++r) inv[r] = 1.f / __shfl(lrow, l4 * 4 + r);
#pragma unroll
    for (int dc = 0; dc < 4; ++dc) {
#pragma unroll
      for (int r = 0; r < 4; ++r) {
        int t = q0 + w * 16 + l4 * 4 + r;
        AO[((size_t)(b * 2048 + t)) * 1024 + h * 64 + dc * 16 + l15] =
            f2b(o[dc][r] * inv[r]);
      }
    }
  };

  run(31 - p);   // heavy q-tile
  run(p);        // light q-tile  -> uniform 33 KV-tiles per block
}

// ---------------------------------------------------------------------------
extern "C" void kernel_launch(void* const* d_in, const int* in_sizes, int n_in,
                              void* d_out, int out_size, void* d_ws, size_t ws_size,
                              hipStream_t stream) {
  const float* x      = (const float*)d_in[0];   // [4,2048,1024]
  const float* w_qkv  = (const float*)d_in[1];   // [1024,3072]
  const float* w_proj = (const float*)d_in[2];   // [1024,1024]
  float* out = (float*)d_out;                    // [4,2048,1024] f32
  char* ws = (char*)d_ws;
  const size_t MB = 1024 * 1024;
  // xb and vT alias (vT written after GEMM1 consumed xb); ao aliases v.
  unsigned short* xb     = (unsigned short*)(ws);            // 16MB [8192][1024]
  unsigned short* vT     = (unsigned short*)(ws);            // 16MB [64][64][2048]
  unsigned short* wqkvT  = (unsigned short*)(ws + 16 * MB);  // 6MB [3072][1024]
  unsigned short* wprojT = (unsigned short*)(ws + 22 * MB);  // 2MB [1024][1024]
  unsigned short* q      = (unsigned short*)(ws + 24 * MB);  // 16MB [64][2048][64]
  unsigned short* k      = (unsigned short*)(ws + 40 * MB);  // 16MB
  unsigned short* v      = (unsigned short*)(ws + 56 * MB);  // 16MB
  unsigned short* ao     = (unsigned short*)(ws + 56 * MB);  // 16MB [8192][1024]

  k_cast_bf16<<<4096, 256, 0, stream>>>(x, xb, 1048576);
  k_transpose_w<<<dim3(48, 16), 256, 0, stream>>>(w_qkv, wqkvT, 1024, 3072);
  k_transpose_w<<<dim3(16, 16), 256, 0, stream>>>(w_proj, wprojT, 1024, 1024);
  const float qscale = 0.125f * 1.44269504088896f;  // hd^-0.5 * log2(e)
  k_gemm<0><<<dim3(24, 64), 256, 0, stream>>>(xb, wqkvT, 8192, 3072, 1024,
                                              nullptr, q, k, v, qscale);
  k_transpose_v<<<dim3(32, 64), 256, 0, stream>>>(v, vT);
  k_attn<<<1024, 256, 0, stream>>>(q, k, vT, ao);
  k_gemm<1><<<dim3(8, 64), 256, 0, stream>>>(ao, wprojT, 8192, 1024, 1024,
                                             out, nullptr, nullptr, nullptr, 1.f);
}

// Round 7
// 202.370 us; speedup vs baseline: 1.0513x; 1.0513x over previous
//
#include <hip/hip_runtime.h>
#include <stdint.h>

// ---------------------------------------------------------------------------
// CausalSelfAttention fused pipeline for MI355X (gfx950)
//   B=4, T=2048, C=1024, H=16, hd=64
// Round 7: k_attn reverted to round-5 config (T13 defer-max removed — it
//          regressed 90->103 via broken cross-tile scheduling). k_gemm keeps
//          counted-vmcnt dbuf + new XCD-chunked bijective block remap
//          (each XCD keeps one B-panel L2-resident).
// ---------------------------------------------------------------------------

typedef __bf16 bf16x8 __attribute__((ext_vector_type(8)));
typedef float f32x4 __attribute__((ext_vector_type(4)));
typedef unsigned short u16x8 __attribute__((ext_vector_type(8)));

#define DEVINL static __device__ __forceinline__

DEVINL unsigned short f2b(float f) {
  __bf16 h = (__bf16)f;           // RNE
  return __builtin_bit_cast(unsigned short, h);
}

DEVINL void gld16(const void* g, void* l) {
  __builtin_amdgcn_global_load_lds(
      (const __attribute__((address_space(1))) void*)g,
      (__attribute__((address_space(3))) void*)l, 16, 0, 0);
}

DEVINL f32x4 mfma16(bf16x8 a, bf16x8 b, f32x4 c) {
  return __builtin_amdgcn_mfma_f32_16x16x32_bf16(a, b, c, 0, 0, 0);
}

#define SCHED_FENCE() __builtin_amdgcn_sched_barrier(0)

// ---------------------------------------------------------------- cast x->bf16
__global__ __launch_bounds__(256) void k_cast_bf16(const float* __restrict__ in,
                                                   unsigned short* __restrict__ out,
                                                   int n8) {
  int i = blockIdx.x * 256 + threadIdx.x;
  if (i >= n8) return;
  const float4* p = (const float4*)in + (size_t)i * 2;
  float4 a = p[0], b = p[1];
  u16x8 o;
  o[0] = f2b(a.x); o[1] = f2b(a.y); o[2] = f2b(a.z); o[3] = f2b(a.w);
  o[4] = f2b(b.x); o[5] = f2b(b.y); o[6] = f2b(b.z); o[7] = f2b(b.w);
  *(u16x8*)(out + (size_t)i * 8) = o;
}

// ------------------------------------------- W [R][C] f32 -> Wt [C][R] bf16
__global__ __launch_bounds__(256) void k_transpose_w(const float* __restrict__ in,
                                                     unsigned short* __restrict__ out,
                                                     int R, int C) {
  __shared__ float t[64][65];
  int ci = blockIdx.x * 64, ri = blockIdx.y * 64;
  int tid = threadIdx.x;
#pragma unroll
  for (int j = 0; j < 4; ++j) {
    int c = tid + j * 256;           // 0..1023 float4 chunks of the 64x64 tile
    int row = c >> 4;
    int col = (c & 15) * 4;
    float4 v = *(const float4*)(in + (size_t)(ri + row) * C + ci + col);
    t[row][col] = v.x; t[row][col + 1] = v.y; t[row][col + 2] = v.z; t[row][col + 3] = v.w;
  }
  __syncthreads();
  int cc = tid >> 2;                 // output row (C index), 0..63
  int seg = (tid & 3) * 16;
  u16x8 o0, o1;
#pragma unroll
  for (int j = 0; j < 8; ++j) o0[j] = f2b(t[seg + j][cc]);
#pragma unroll
  for (int j = 0; j < 8; ++j) o1[j] = f2b(t[seg + 8 + j][cc]);
  unsigned short* dst = out + (size_t)(ci + cc) * R + ri + seg;
  *(u16x8*)dst = o0;
  *(u16x8*)(dst + 8) = o1;
}

// --------------------------------- V [bh][2048][64] -> Vt [bh][64][2048] bf16
__global__ __launch_bounds__(256) void k_transpose_v(const unsigned short* __restrict__ v,
                                                     unsigned short* __restrict__ vt) {
  __shared__ unsigned short s[64][65];
  int bh = blockIdx.y;
  int t0 = blockIdx.x * 64;
  int tid = threadIdx.x;
  const unsigned short* src = v + ((size_t)bh * 2048 + t0) * 64;
#pragma unroll
  for (int j = 0; j < 2; ++j) {
    int c = tid + j * 256;           // 0..511 (16B chunks of 64x64 bf16 tile)
    int row = c >> 3;
    int col = (c & 7) * 8;
    u16x8 x = *(const u16x8*)(src + (size_t)row * 64 + col);
#pragma unroll
    for (int q = 0; q < 8; ++q) s[row][col + q] = x[q];
  }
  __syncthreads();
  int d = tid >> 2;                  // 0..63
  int seg = (tid & 3) * 16;
  u16x8 o0, o1;
#pragma unroll
  for (int j = 0; j < 8; ++j) o0[j] = s[seg + j][d];
#pragma unroll
  for (int j = 0; j < 8; ++j) o1[j] = s[seg + 8 + j][d];
  unsigned short* dst = vt + ((size_t)bh * 64 + d) * 2048 + t0 + seg;
  *(u16x8*)dst = o0;
  *(u16x8*)(dst + 8) = o1;
}

// ---------------------------------------------------------------- GEMM (A Bt)
// A [M][K] bf16, Bt [N][K] bf16. 128x128 tile, BK=32, 4 waves (2x2 of 64x64).
// Counted-vmcnt dbuf K-loop. 1D grid + bijective XCD-chunked remap: blocks
// within one XCD get consecutive wgid -> same bn column (B-panel L2-hot).
// MODE 0: scatter into q/k/v per-head layout (q scaled). MODE 1: fp32 C out.
template <int MODE>
__global__ __launch_bounds__(256) void k_gemm(const unsigned short* __restrict__ A,
                                              const unsigned short* __restrict__ Bt,
                                              int M, int N, int K,
                                              float* __restrict__ Cf,
                                              unsigned short* __restrict__ qo,
                                              unsigned short* __restrict__ ko,
                                              unsigned short* __restrict__ vo,
                                              float qscale) {
  __shared__ unsigned short As[2][128 * 32];   // 16 KB
  __shared__ unsigned short Bs[2][128 * 32];   // 16 KB
  int tid = threadIdx.x;
  int w = tid >> 6, lane = tid & 63, l15 = lane & 15, l4 = lane >> 4;
  // bijective XCD chunk remap (m204): xcd = lin&7 under round-robin dispatch
  int nwg = gridDim.x;
  int gy = M >> 7;
  int lin = blockIdx.x;
  int nx = nwg >> 3, rr = nwg & 7;
  int xcd = lin & 7, idx = lin >> 3;
  int wgid = (xcd < rr ? xcd * (nx + 1) : rr * (nx + 1) + (xcd - rr) * nx) + idx;
  int bn = wgid / gy, bm = wgid % gy;   // bm-major within XCD -> bn chunked
  int wr = (w >> 1) * 64, wc = (w & 1) * 64;
  f32x4 acc[4][4];
#pragma unroll
  for (int i = 0; i < 4; ++i)
#pragma unroll
    for (int j = 0; j < 4; ++j) acc[i][j] = (f32x4){0.f, 0.f, 0.f, 0.f};
  const char* Ab = (const char*)(A + (size_t)bm * 128 * K);
  const char* Bb = (const char*)(Bt + (size_t)bn * 128 * K);
  // per-thread staging chunks (4 gld16 per K-step)
  int c_0 = tid, c_1 = tid + 256;
  int row0 = c_0 >> 2, cb0 = (c_0 & 3) * 16;
  int row1 = c_1 >> 2, cb1 = (c_1 & 3) * 16;

  auto stage = [&](int kt, int buf) {
    gld16(Ab + ((size_t)row0 * K + kt) * 2 + cb0, (char*)As[buf] + c_0 * 16);
    gld16(Bb + ((size_t)row0 * K + kt) * 2 + cb0, (char*)Bs[buf] + c_0 * 16);
    gld16(Ab + ((size_t)row1 * K + kt) * 2 + cb1, (char*)As[buf] + c_1 * 16);
    gld16(Bb + ((size_t)row1 * K + kt) * 2 + cb1, (char*)Bs[buf] + c_1 * 16);
  };

  const int nkt = K >> 5;
  stage(0, 0);
  SCHED_FENCE();
  for (int t = 0; t < nkt; ++t) {
    int cur = t & 1;
    if (t) {                           // WAR: all waves done reading buf[cur^1]
      SCHED_FENCE();
      __builtin_amdgcn_s_barrier();
      SCHED_FENCE();
    }
    if (t + 1 < nkt) {
      stage((t + 1) * 32, cur ^ 1);
      SCHED_FENCE();
      asm volatile("s_waitcnt vmcnt(4)" ::: "memory");  // step t's loads done
    } else {
      SCHED_FENCE();
      asm volatile("s_waitcnt vmcnt(0)" ::: "memory");
    }
    SCHED_FENCE();
    __builtin_amdgcn_s_barrier();      // RAW: buf[cur] ready for all waves
    SCHED_FENCE();
    const char* Ac = (const char*)As[cur];
    const char* Bc = (const char*)Bs[cur];
    bf16x8 af[4], bfr[4];
#pragma unroll
    for (int m = 0; m < 4; ++m)
      af[m] = *(const bf16x8*)(Ac + (wr + m * 16 + l15) * 64 + l4 * 16);
#pragma unroll
    for (int n = 0; n < 4; ++n)
      bfr[n] = *(const bf16x8*)(Bc + (wc + n * 16 + l15) * 64 + l4 * 16);
    __builtin_amdgcn_s_setprio(1);
#pragma unroll
    for (int m = 0; m < 4; ++m)
#pragma unroll
      for (int n = 0; n < 4; ++n)
        acc[m][n] = mfma16(af[m], bfr[n], acc[m][n]);
    __builtin_amdgcn_s_setprio(0);
  }
  // epilogue: D col = lane&15, row = (lane>>4)*4 + reg  [m89-verified]
#pragma unroll
  for (int m = 0; m < 4; ++m) {
    int grow0 = bm * 128 + wr + m * 16 + l4 * 4;
#pragma unroll
    for (int n = 0; n < 4; ++n) {
      int gcol = bn * 128 + wc + n * 16 + l15;
#pragma unroll
      for (int r = 0; r < 4; ++r) {
        int grow = grow0 + r;
        float val = acc[m][n][r];
        if (MODE == 1) {
          Cf[(size_t)grow * N + gcol] = val;
        } else {
          int which = gcol >> 10, rem = gcol & 1023;
          int h = rem >> 6, d = rem & 63;
          int b = grow >> 11, t = grow & 2047;
          size_t off = (((size_t)(b * 16 + h)) * 2048 + t) * 64 + d;
          if (which == 0)      qo[off] = f2b(val * qscale);
          else if (which == 1) ko[off] = f2b(val);
          else                 vo[off] = f2b(val);
        }
      }
    }
  }
}

// ------------------------------------------------------------ flash attention
// Q,K: [bh][2048][64] bf16 (Q pre-scaled by 0.125*log2e); Vt: [bh][64][2048].
// 4 waves x 16 q-rows per q-tile; each block runs TWO q-tiles (31-p then p)
// -> uniform 33 KV-tiles per block. K/V double-buffered in LDS; counted
// s_waitcnt vmcnt(4) + raw s_barrier (loads for tile t+1 stay in flight
// across the barrier). LDS XOR swizzle: byte ^ ((row&7)<<4).
__global__ __launch_bounds__(256) void k_attn(const unsigned short* __restrict__ Q,
                                              const unsigned short* __restrict__ Kt,
                                              const unsigned short* __restrict__ Vt,
                                              unsigned short* __restrict__ AO) {
  __shared__ unsigned short Ks[2][4096];   // 16 KB  [64 kv][64 d]
  __shared__ unsigned short Vs[2][4096];   // 16 KB  [64 d][64 kv]
  __shared__ unsigned short Ps[4096];      //  8 KB  4 waves x [16 q][64 kv]
  int tid = threadIdx.x;
  int w = tid >> 6, lane = tid & 63, l15 = lane & 15, l4 = lane >> 4;
  // XCD-pinned mapping (perf heuristic): 8 heads per XCD -> 4MB KV per L2.
  int lin = blockIdx.x;
  int xcd = lin & 7, jj = lin >> 3;
  int bh = xcd * 8 + (jj & 7);
  int p = jj >> 3;                       // 0..15: q-tile pair (31-p, p)
  const char* Kb = (const char*)(Kt + (size_t)bh * 2048 * 64);
  const char* Vb = (const char*)(Vt + (size_t)bh * 64 * 2048);
  const int swp = (l15 & 7) << 4;        // P-row swizzle for this lane
  char* Pw = (char*)Ps + w * 2048;
  int b = bh >> 4, h = bh & 15;

  // per-lane staging addresses (2 slices per wave), both-sides swizzle
  int Lb0 = (w * 64 + lane) * 16;
  int Lb1 = ((w + 4) * 64 + lane) * 16;
  int Nb0 = Lb0 ^ (((Lb0 >> 7) & 7) << 4);
  int Nb1 = Lb1 ^ (((Lb1 >> 7) & 7) << 4);
  int d0 = Nb0 >> 7, in0 = Nb0 & 127;
  int d1 = Nb1 >> 7, in1 = Nb1 & 127;

  auto stage = [&](int t, int buf) {
    size_t kv0 = (size_t)t * 64;
    gld16(Kb + kv0 * 128 + Nb0, (char*)Ks[buf] + Lb0);
    gld16(Vb + (size_t)d0 * 4096 + kv0 * 2 + in0, (char*)Vs[buf] + Lb0);
    gld16(Kb + kv0 * 128 + Nb1, (char*)Ks[buf] + Lb1);
    gld16(Vb + (size_t)d1 * 4096 + kv0 * 2 + in1, (char*)Vs[buf] + Lb1);
  };

  auto run = [&](int qi) {
    int q0 = qi * 64;
    const unsigned short* Qb = Q + ((size_t)bh * 2048 + q0 + w * 16) * 64;
    bf16x8 qf0 = *(const bf16x8*)((const char*)Qb + l15 * 128 + l4 * 16);
    bf16x8 qf1 = *(const bf16x8*)((const char*)Qb + l15 * 128 + 64 + l4 * 16);
    f32x4 o[4];
#pragma unroll
    for (int i = 0; i < 4; ++i) o[i] = (f32x4){0.f, 0.f, 0.f, 0.f};
    float mrow = -1e30f, lrow = 0.f;     // per-lane state for q = l15
    const int ntiles = qi + 1;
    const int qg = w * 16 + l15;
    // WAR barrier vs previous run's reads, then stage tile 0 into buf 0
    SCHED_FENCE();
    __builtin_amdgcn_s_barrier();
    SCHED_FENCE();
    stage(0, 0);
    SCHED_FENCE();
    for (int it = 0; it < ntiles; ++it) {
      int cur = it & 1;
      if (it) {                          // WAR: all waves done reading buf[cur^1]
        SCHED_FENCE();
        __builtin_amdgcn_s_barrier();
        SCHED_FENCE();
      }
      if (it + 1 < ntiles) {
        stage(it + 1, cur ^ 1);
        SCHED_FENCE();
        asm volatile("s_waitcnt vmcnt(4)" ::: "memory");  // tile it complete
      } else {
        SCHED_FENCE();
        asm volatile("s_waitcnt vmcnt(0)" ::: "memory");  // last tile: drain
      }
      SCHED_FENCE();
      __builtin_amdgcn_s_barrier();      // RAW: buf[cur] ready for all waves
      SCHED_FENCE();
      const char* Kc = (const char*)Ks[cur];
      const char* Vc = (const char*)Vs[cur];
      // S^T = K Q^T: lane holds s[c][r] = S[q=l15][kv=c*16+l4*4+r]
      f32x4 s[4];
      __builtin_amdgcn_s_setprio(1);
#pragma unroll
      for (int c = 0; c < 4; ++c) {
        int row = c * 16 + l15;
        int base = row * 128 + l4 * 16;
        int sw = (row & 7) << 4;
        bf16x8 k0 = *(const bf16x8*)(Kc + (base ^ sw));
        bf16x8 k1 = *(const bf16x8*)(Kc + ((base + 64) ^ sw));
        f32x4 t = mfma16(k0, qf0, (f32x4){0.f, 0.f, 0.f, 0.f});
        s[c] = mfma16(k1, qf1, t);
      }
      __builtin_amdgcn_s_setprio(0);
      if (it == ntiles - 1) {            // diagonal tile: causal mask
#pragma unroll
        for (int c = 0; c < 4; ++c) {
          int kvb = c * 16 + l4 * 4;
#pragma unroll
          for (int r = 0; r < 4; ++r)
            if (kvb + r > qg) s[c][r] = -1e30f;
        }
      }
      // online softmax: lane-local 16 + 2 shuffles
      float mx = fmaxf(fmaxf(fmaxf(s[0][0], s[0][1]), fmaxf(s[0][2], s[0][3])),
                       fmaxf(fmaxf(s[1][0], s[1][1]), fmaxf(s[1][2], s[1][3])));
      mx = fmaxf(mx, fmaxf(fmaxf(fmaxf(s[2][0], s[2][1]), fmaxf(s[2][2], s[2][3])),
                           fmaxf(fmaxf(s[3][0], s[3][1]), fmaxf(s[3][2], s[3][3]))));
      mx = fmaxf(mx, __shfl_xor(mx, 16));
      mx = fmaxf(mx, __shfl_xor(mx, 32));
      float mn = fmaxf(mrow, mx);
      float corr = __builtin_amdgcn_exp2f(mrow - mn);
      mrow = mn;
      float rs = 0.f;
#pragma unroll
      for (int c = 0; c < 4; ++c) {
        float p0 = __builtin_amdgcn_exp2f(s[c][0] - mn);
        float p1 = __builtin_amdgcn_exp2f(s[c][1] - mn);
        float p2 = __builtin_amdgcn_exp2f(s[c][2] - mn);
        float p3 = __builtin_amdgcn_exp2f(s[c][3] - mn);
        rs += (p0 + p1) + (p2 + p3);
        uint32_t lo = (uint32_t)f2b(p0) | ((uint32_t)f2b(p1) << 16);
        uint32_t hi = (uint32_t)f2b(p2) | ((uint32_t)f2b(p3) << 16);
        *(uint2*)(Pw + ((l15 * 128 + c * 32 + l4 * 8) ^ swp)) = make_uint2(lo, hi);
      }
      rs += __shfl_xor(rs, 16);
      rs += __shfl_xor(rs, 32);
      lrow = lrow * corr + rs;
      float corr_r[4];
#pragma unroll
      for (int r = 0; r < 4; ++r) corr_r[r] = __shfl(corr, l4 * 4 + r);
#pragma unroll
      for (int dc = 0; dc < 4; ++dc)
#pragma unroll
        for (int r = 0; r < 4; ++r) o[dc][r] *= corr_r[r];
      // O += P V
      bf16x8 pa[2];
#pragma unroll
      for (int kc = 0; kc < 2; ++kc)
        pa[kc] = *(const bf16x8*)(Pw + ((l15 * 128 + kc * 64 + l4 * 16) ^ swp));
      __builtin_amdgcn_s_setprio(1);
#pragma unroll
      for (int dc = 0; dc < 4; ++dc) {
#pragma unroll
        for (int kc = 0; kc < 2; ++kc) {
          int vrow = dc * 16 + l15;
          int vnat = vrow * 128 + kc * 64 + l4 * 16;
          bf16x8 vb = *(const bf16x8*)(Vc + (vnat ^ ((vrow & 7) << 4)));
          o[dc] = mfma16(pa[kc], vb, o[dc]);
        }
      }
      __builtin_amdgcn_s_setprio(0);
    }
    float inv[4];
#pragma unroll
    for (int r = 0; r < 4; ++r) inv[r] = 1.f / __shfl(lrow, l4 * 4 + r);
#pragma unroll
    for (int dc = 0; dc < 4; ++dc) {
#pragma unroll
      for (int r = 0; r < 4; ++r) {
        int t = q0 + w * 16 + l4 * 4 + r;
        AO[((size_t)(b * 2048 + t)) * 1024 + h * 64 + dc * 16 + l15] =
            f2b(o[dc][r] * inv[r]);
      }
    }
  };

  run(31 - p);   // heavy q-tile
  run(p);        // light q-tile  -> uniform 33 KV-tiles per block
}

// ---------------------------------------------------------------------------
extern "C" void kernel_launch(void* const* d_in, const int* in_sizes, int n_in,
                              void* d_out, int out_size, void* d_ws, size_t ws_size,
                              hipStream_t stream) {
  const float* x      = (const float*)d_in[0];   // [4,2048,1024]
  const float* w_qkv  = (const float*)d_in[1];   // [1024,3072]
  const float* w_proj = (const float*)d_in[2];   // [1024,1024]
  float* out = (float*)d_out;                    // [4,2048,1024] f32
  char* ws = (char*)d_ws;
  const size_t MB = 1024 * 1024;
  // xb and vT alias (vT written after GEMM1 consumed xb); ao aliases v.
  unsigned short* xb     = (unsigned short*)(ws);            // 16MB [8192][1024]
  unsigned short* vT     = (unsigned short*)(ws);            // 16MB [64][64][2048]
  unsigned short* wqkvT  = (unsigned short*)(ws + 16 * MB);  // 6MB [3072][1024]
  unsigned short* wprojT = (unsigned short*)(ws + 22 * MB);  // 2MB [1024][1024]
  unsigned short* q      = (unsigned short*)(ws + 24 * MB);  // 16MB [64][2048][64]
  unsigned short* k      = (unsigned short*)(ws + 40 * MB);  // 16MB
  unsigned short* v      = (unsigned short*)(ws + 56 * MB);  // 16MB
  unsigned short* ao     = (unsigned short*)(ws + 56 * MB);  // 16MB [8192][1024]

  k_cast_bf16<<<4096, 256, 0, stream>>>(x, xb, 1048576);
  k_transpose_w<<<dim3(48, 16), 256, 0, stream>>>(w_qkv, wqkvT, 1024, 3072);
  k_transpose_w<<<dim3(16, 16), 256, 0, stream>>>(w_proj, wprojT, 1024, 1024);
  const float qscale = 0.125f * 1.44269504088896f;  // hd^-0.5 * log2(e)
  k_gemm<0><<<1536, 256, 0, stream>>>(xb, wqkvT, 8192, 3072, 1024,
                                      nullptr, q, k, v, qscale);
  k_transpose_v<<<dim3(32, 64), 256, 0, stream>>>(v, vT);
  k_attn<<<1024, 256, 0, stream>>>(q, k, vT, ao);
  k_gemm<1><<<512, 256, 0, stream>>>(ao, wprojT, 8192, 1024, 1024,
                                     out, nullptr, nullptr, nullptr, 1.f);
}

// Round 8
// 190.689 us; speedup vs baseline: 1.1157x; 1.0613x over previous
//
#include <hip/hip_runtime.h>
#include <stdint.h>

// ---------------------------------------------------------------------------
// CausalSelfAttention fused pipeline for MI355X (gfx950)
//   B=4, T=2048, C=1024, H=16, hd=64
// Round 8: (1) GEMM1 epilogue writes V^T directly (packed 8B stores of 4
//          consecutive-t bf16) -> k_transpose_v kernel deleted.
//          (2) k_attn QBLK=128 with 8 waves/512 threads: each staged K/V
//          tile feeds 2x the q-rows (staging+barriers per score halved);
//          fully-masked waves skip compute (wave-uniform branch).
// ---------------------------------------------------------------------------

typedef __bf16 bf16x8 __attribute__((ext_vector_type(8)));
typedef float f32x4 __attribute__((ext_vector_type(4)));
typedef unsigned short u16x8 __attribute__((ext_vector_type(8)));

#define DEVINL static __device__ __forceinline__

DEVINL unsigned short f2b(float f) {
  __bf16 h = (__bf16)f;           // RNE
  return __builtin_bit_cast(unsigned short, h);
}

DEVINL void gld16(const void* g, void* l) {
  __builtin_amdgcn_global_load_lds(
      (const __attribute__((address_space(1))) void*)g,
      (__attribute__((address_space(3))) void*)l, 16, 0, 0);
}

DEVINL f32x4 mfma16(bf16x8 a, bf16x8 b, f32x4 c) {
  return __builtin_amdgcn_mfma_f32_16x16x32_bf16(a, b, c, 0, 0, 0);
}

#define SCHED_FENCE() __builtin_amdgcn_sched_barrier(0)

// ---------------------------------------------------------------- cast x->bf16
__global__ __launch_bounds__(256) void k_cast_bf16(const float* __restrict__ in,
                                                   unsigned short* __restrict__ out,
                                                   int n8) {
  int i = blockIdx.x * 256 + threadIdx.x;
  if (i >= n8) return;
  const float4* p = (const float4*)in + (size_t)i * 2;
  float4 a = p[0], b = p[1];
  u16x8 o;
  o[0] = f2b(a.x); o[1] = f2b(a.y); o[2] = f2b(a.z); o[3] = f2b(a.w);
  o[4] = f2b(b.x); o[5] = f2b(b.y); o[6] = f2b(b.z); o[7] = f2b(b.w);
  *(u16x8*)(out + (size_t)i * 8) = o;
}

// ------------------------------------------- W [R][C] f32 -> Wt [C][R] bf16
__global__ __launch_bounds__(256) void k_transpose_w(const float* __restrict__ in,
                                                     unsigned short* __restrict__ out,
                                                     int R, int C) {
  __shared__ float t[64][65];
  int ci = blockIdx.x * 64, ri = blockIdx.y * 64;
  int tid = threadIdx.x;
#pragma unroll
  for (int j = 0; j < 4; ++j) {
    int c = tid + j * 256;           // 0..1023 float4 chunks of the 64x64 tile
    int row = c >> 4;
    int col = (c & 15) * 4;
    float4 v = *(const float4*)(in + (size_t)(ri + row) * C + ci + col);
    t[row][col] = v.x; t[row][col + 1] = v.y; t[row][col + 2] = v.z; t[row][col + 3] = v.w;
  }
  __syncthreads();
  int cc = tid >> 2;                 // output row (C index), 0..63
  int seg = (tid & 3) * 16;
  u16x8 o0, o1;
#pragma unroll
  for (int j = 0; j < 8; ++j) o0[j] = f2b(t[seg + j][cc]);
#pragma unroll
  for (int j = 0; j < 8; ++j) o1[j] = f2b(t[seg + 8 + j][cc]);
  unsigned short* dst = out + (size_t)(ci + cc) * R + ri + seg;
  *(u16x8*)dst = o0;
  *(u16x8*)(dst + 8) = o1;
}

// ---------------------------------------------------------------- GEMM (A Bt)
// A [M][K] bf16, Bt [N][K] bf16. 128x128 tile, BK=32, 4 waves (2x2 of 64x64).
// Counted-vmcnt dbuf K-loop; bijective XCD-chunked 1D remap.
// MODE 0: scatter q/k per-head [bh][t][d] (q scaled) and V TRANSPOSED
//         [bh][d][t] via packed 8B stores. MODE 1: fp32 C out.
template <int MODE>
__global__ __launch_bounds__(256) void k_gemm(const unsigned short* __restrict__ A,
                                              const unsigned short* __restrict__ Bt,
                                              int M, int N, int K,
                                              float* __restrict__ Cf,
                                              unsigned short* __restrict__ qo,
                                              unsigned short* __restrict__ ko,
                                              unsigned short* __restrict__ vo,
                                              float qscale) {
  __shared__ unsigned short As[2][128 * 32];   // 16 KB
  __shared__ unsigned short Bs[2][128 * 32];   // 16 KB
  int tid = threadIdx.x;
  int w = tid >> 6, lane = tid & 63, l15 = lane & 15, l4 = lane >> 4;
  // bijective XCD chunk remap (m204): xcd = lin&7 under round-robin dispatch
  int nwg = gridDim.x;
  int gy = M >> 7;
  int lin = blockIdx.x;
  int nx = nwg >> 3, rr = nwg & 7;
  int xcd = lin & 7, idx = lin >> 3;
  int wgid = (xcd < rr ? xcd * (nx + 1) : rr * (nx + 1) + (xcd - rr) * nx) + idx;
  int bn = wgid / gy, bm = wgid % gy;   // bm-major within XCD -> bn chunked
  int wr = (w >> 1) * 64, wc = (w & 1) * 64;
  f32x4 acc[4][4];
#pragma unroll
  for (int i = 0; i < 4; ++i)
#pragma unroll
    for (int j = 0; j < 4; ++j) acc[i][j] = (f32x4){0.f, 0.f, 0.f, 0.f};
  const char* Ab = (const char*)(A + (size_t)bm * 128 * K);
  const char* Bb = (const char*)(Bt + (size_t)bn * 128 * K);
  // per-thread staging chunks (4 gld16 per K-step)
  int c_0 = tid, c_1 = tid + 256;
  int row0 = c_0 >> 2, cb0 = (c_0 & 3) * 16;
  int row1 = c_1 >> 2, cb1 = (c_1 & 3) * 16;

  auto stage = [&](int kt, int buf) {
    gld16(Ab + ((size_t)row0 * K + kt) * 2 + cb0, (char*)As[buf] + c_0 * 16);
    gld16(Bb + ((size_t)row0 * K + kt) * 2 + cb0, (char*)Bs[buf] + c_0 * 16);
    gld16(Ab + ((size_t)row1 * K + kt) * 2 + cb1, (char*)As[buf] + c_1 * 16);
    gld16(Bb + ((size_t)row1 * K + kt) * 2 + cb1, (char*)Bs[buf] + c_1 * 16);
  };

  const int nkt = K >> 5;
  stage(0, 0);
  SCHED_FENCE();
  for (int t = 0; t < nkt; ++t) {
    int cur = t & 1;
    if (t) {                           // WAR: all waves done reading buf[cur^1]
      SCHED_FENCE();
      __builtin_amdgcn_s_barrier();
      SCHED_FENCE();
    }
    if (t + 1 < nkt) {
      stage((t + 1) * 32, cur ^ 1);
      SCHED_FENCE();
      asm volatile("s_waitcnt vmcnt(4)" ::: "memory");  // step t's loads done
    } else {
      SCHED_FENCE();
      asm volatile("s_waitcnt vmcnt(0)" ::: "memory");
    }
    SCHED_FENCE();
    __builtin_amdgcn_s_barrier();      // RAW: buf[cur] ready for all waves
    SCHED_FENCE();
    const char* Ac = (const char*)As[cur];
    const char* Bc = (const char*)Bs[cur];
    bf16x8 af[4], bfr[4];
#pragma unroll
    for (int m = 0; m < 4; ++m)
      af[m] = *(const bf16x8*)(Ac + (wr + m * 16 + l15) * 64 + l4 * 16);
#pragma unroll
    for (int n = 0; n < 4; ++n)
      bfr[n] = *(const bf16x8*)(Bc + (wc + n * 16 + l15) * 64 + l4 * 16);
    __builtin_amdgcn_s_setprio(1);
#pragma unroll
    for (int m = 0; m < 4; ++m)
#pragma unroll
      for (int n = 0; n < 4; ++n)
        acc[m][n] = mfma16(af[m], bfr[n], acc[m][n]);
    __builtin_amdgcn_s_setprio(0);
  }
  // epilogue: D col = lane&15, row = (lane>>4)*4 + reg  [m89-verified]
#pragma unroll
  for (int m = 0; m < 4; ++m) {
    int grow0 = bm * 128 + wr + m * 16 + l4 * 4;
#pragma unroll
    for (int n = 0; n < 4; ++n) {
      int gcol = bn * 128 + wc + n * 16 + l15;
      if (MODE == 1) {
#pragma unroll
        for (int r = 0; r < 4; ++r)
          Cf[(size_t)(grow0 + r) * N + gcol] = acc[m][n][r];
      } else {
        int which = gcol >> 10, rem = gcol & 1023;
        int h = rem >> 6, d = rem & 63;
        int b = grow0 >> 11, t0 = grow0 & 2047;
        if (which == 2) {
          // V^T [bh][d][t]: 4 consecutive-t bf16 -> one 8B store
          uint32_t lo = (uint32_t)f2b(acc[m][n][0]) | ((uint32_t)f2b(acc[m][n][1]) << 16);
          uint32_t hi = (uint32_t)f2b(acc[m][n][2]) | ((uint32_t)f2b(acc[m][n][3]) << 16);
          size_t off = (((size_t)(b * 16 + h)) * 64 + d) * 2048 + t0;
          *(uint2*)(vo + off) = make_uint2(lo, hi);
        } else {
          size_t off = (((size_t)(b * 16 + h)) * 2048 + t0) * 64 + d;
#pragma unroll
          for (int r = 0; r < 4; ++r) {
            float val = acc[m][n][r];
            if (which == 0) qo[off + (size_t)r * 64] = f2b(val * qscale);
            else            ko[off + (size_t)r * 64] = f2b(val);
          }
        }
      }
    }
  }
}

// ------------------------------------------------------------ flash attention
// Q,K: [bh][2048][64] bf16 (Q pre-scaled by 0.125*log2e); Vt: [bh][64][2048].
// 8 waves x 16 q-rows (QBLK=128); each block runs q-tiles (15-p, p) ->
// uniform 34 KV-tiles/block. K/V double-buffered in LDS; counted
// s_waitcnt vmcnt(2) + raw s_barrier. Fully-masked waves skip compute.
// LDS XOR swizzle: byte ^ ((row&7)<<4).
__global__ __launch_bounds__(512) void k_attn(const unsigned short* __restrict__ Q,
                                              const unsigned short* __restrict__ Kt,
                                              const unsigned short* __restrict__ Vt,
                                              unsigned short* __restrict__ AO) {
  __shared__ unsigned short Ks[2][4096];   // 16 KB  [64 kv][64 d]
  __shared__ unsigned short Vs[2][4096];   // 16 KB  [64 d][64 kv]
  __shared__ unsigned short Ps[8192];      // 16 KB  8 waves x [16 q][64 kv]
  int tid = threadIdx.x;
  int w = tid >> 6, lane = tid & 63, l15 = lane & 15, l4 = lane >> 4;
  // XCD-pinned mapping (perf heuristic): 8 heads per XCD -> 4MB KV per L2.
  int lin = blockIdx.x;
  int xcd = lin & 7, jj = lin >> 3;
  int bh = xcd * 8 + (jj & 7);
  int p = jj >> 3;                       // 0..7: q-tile pair (15-p, p)
  const char* Kb = (const char*)(Kt + (size_t)bh * 2048 * 64);
  const char* Vb = (const char*)(Vt + (size_t)bh * 64 * 2048);
  const int swp = (l15 & 7) << 4;        // P-row swizzle for this lane
  char* Pw = (char*)Ps + w * 2048;
  int b = bh >> 4, h = bh & 15;

  // per-thread staging addresses (512 threads cover each 8KB tile once)
  int Lb0 = tid * 16;
  int Nb0 = Lb0 ^ (((Lb0 >> 7) & 7) << 4);
  int d0 = Nb0 >> 7, in0 = Nb0 & 127;

  auto stage = [&](int t, int buf) {
    size_t kv0 = (size_t)t * 64;
    gld16(Kb + kv0 * 128 + Nb0, (char*)Ks[buf] + Lb0);
    gld16(Vb + (size_t)d0 * 4096 + kv0 * 2 + in0, (char*)Vs[buf] + Lb0);
  };

  auto run = [&](int qi) {
    int q0 = qi * 128;
    const unsigned short* Qb = Q + ((size_t)bh * 2048 + q0 + w * 16) * 64;
    bf16x8 qf0 = *(const bf16x8*)((const char*)Qb + l15 * 128 + l4 * 16);
    bf16x8 qf1 = *(const bf16x8*)((const char*)Qb + l15 * 128 + 64 + l4 * 16);
    f32x4 o[4];
#pragma unroll
    for (int i = 0; i < 4; ++i) o[i] = (f32x4){0.f, 0.f, 0.f, 0.f};
    float mrow = -1e30f, lrow = 0.f;     // per-lane state for q = l15
    const int ntiles = 2 * qi + 2;
    const int qgmin = q0 + w * 16;       // this wave's lowest q row
    const int qg = qgmin + l15;          // per-lane q row
    // WAR barrier vs previous run's reads, then stage tile 0 into buf 0
    SCHED_FENCE();
    __builtin_amdgcn_s_barrier();
    SCHED_FENCE();
    stage(0, 0);
    SCHED_FENCE();
    for (int it = 0; it < ntiles; ++it) {
      int cur = it & 1;
      if (it) {                          // WAR: all waves done reading buf[cur^1]
        SCHED_FENCE();
        __builtin_amdgcn_s_barrier();
        SCHED_FENCE();
      }
      if (it + 1 < ntiles) {
        stage(it + 1, cur ^ 1);
        SCHED_FENCE();
        asm volatile("s_waitcnt vmcnt(2)" ::: "memory");  // tile it complete
      } else {
        SCHED_FENCE();
        asm volatile("s_waitcnt vmcnt(0)" ::: "memory");  // last tile: drain
      }
      SCHED_FENCE();
      __builtin_amdgcn_s_barrier();      // RAW: buf[cur] ready for all waves
      SCHED_FENCE();
      if (it * 64 <= qgmin + 15) {       // wave-uniform: not fully masked
        const char* Kc = (const char*)Ks[cur];
        const char* Vc = (const char*)Vs[cur];
        // S^T = K Q^T: lane holds s[c][r] = S[q=l15][kv=it*64+c*16+l4*4+r]
        f32x4 s[4];
        __builtin_amdgcn_s_setprio(1);
#pragma unroll
        for (int c = 0; c < 4; ++c) {
          int row = c * 16 + l15;
          int base = row * 128 + l4 * 16;
          int sw = (row & 7) << 4;
          bf16x8 k0 = *(const bf16x8*)(Kc + (base ^ sw));
          bf16x8 k1 = *(const bf16x8*)(Kc + ((base + 64) ^ sw));
          f32x4 t = mfma16(k0, qf0, (f32x4){0.f, 0.f, 0.f, 0.f});
          s[c] = mfma16(k1, qf1, t);
        }
        __builtin_amdgcn_s_setprio(0);
        if (it * 64 + 63 > qgmin) {      // diagonal-intersecting tile: mask
#pragma unroll
          for (int c = 0; c < 4; ++c) {
            int kvb = it * 64 + c * 16 + l4 * 4;
#pragma unroll
            for (int r = 0; r < 4; ++r)
              if (kvb + r > qg) s[c][r] = -1e30f;
          }
        }
        // online softmax: lane-local 16 + 2 shuffles
        float mx = fmaxf(fmaxf(fmaxf(s[0][0], s[0][1]), fmaxf(s[0][2], s[0][3])),
                         fmaxf(fmaxf(s[1][0], s[1][1]), fmaxf(s[1][2], s[1][3])));
        mx = fmaxf(mx, fmaxf(fmaxf(fmaxf(s[2][0], s[2][1]), fmaxf(s[2][2], s[2][3])),
                             fmaxf(fmaxf(s[3][0], s[3][1]), fmaxf(s[3][2], s[3][3]))));
        mx = fmaxf(mx, __shfl_xor(mx, 16));
        mx = fmaxf(mx, __shfl_xor(mx, 32));
        float mn = fmaxf(mrow, mx);
        float corr = __builtin_amdgcn_exp2f(mrow - mn);
        mrow = mn;
        float rs = 0.f;
#pragma unroll
        for (int c = 0; c < 4; ++c) {
          float p0 = __builtin_amdgcn_exp2f(s[c][0] - mn);
          float p1 = __builtin_amdgcn_exp2f(s[c][1] - mn);
          float p2 = __builtin_amdgcn_exp2f(s[c][2] - mn);
          float p3 = __builtin_amdgcn_exp2f(s[c][3] - mn);
          rs += (p0 + p1) + (p2 + p3);
          uint32_t lo = (uint32_t)f2b(p0) | ((uint32_t)f2b(p1) << 16);
          uint32_t hi = (uint32_t)f2b(p2) | ((uint32_t)f2b(p3) << 16);
          *(uint2*)(Pw + ((l15 * 128 + c * 32 + l4 * 8) ^ swp)) = make_uint2(lo, hi);
        }
        rs += __shfl_xor(rs, 16);
        rs += __shfl_xor(rs, 32);
        lrow = lrow * corr + rs;
        float corr_r[4];
#pragma unroll
        for (int r = 0; r < 4; ++r) corr_r[r] = __shfl(corr, l4 * 4 + r);
#pragma unroll
        for (int dc = 0; dc < 4; ++dc)
#pragma unroll
          for (int r = 0; r < 4; ++r) o[dc][r] *= corr_r[r];
        // O += P V
        bf16x8 pa[2];
#pragma unroll
        for (int kc = 0; kc < 2; ++kc)
          pa[kc] = *(const bf16x8*)(Pw + ((l15 * 128 + kc * 64 + l4 * 16) ^ swp));
        __builtin_amdgcn_s_setprio(1);
#pragma unroll
        for (int dc = 0; dc < 4; ++dc) {
#pragma unroll
          for (int kc = 0; kc < 2; ++kc) {
            int vrow = dc * 16 + l15;
            int vnat = vrow * 128 + kc * 64 + l4 * 16;
            bf16x8 vb = *(const bf16x8*)(Vc + (vnat ^ ((vrow & 7) << 4)));
            o[dc] = mfma16(pa[kc], vb, o[dc]);
          }
        }
        __builtin_amdgcn_s_setprio(0);
      }
    }
    float inv[4];
#pragma unroll
    for (int r = 0; r < 4; ++r) inv[r] = 1.f / __shfl(lrow, l4 * 4 + r);
#pragma unroll
    for (int dc = 0; dc < 4; ++dc) {
#pragma unroll
      for (int r = 0; r < 4; ++r) {
        int t = q0 + w * 16 + l4 * 4 + r;
        AO[((size_t)(b * 2048 + t)) * 1024 + h * 64 + dc * 16 + l15] =
            f2b(o[dc][r] * inv[r]);
      }
    }
  };

  run(15 - p);   // heavy q-tile
  run(p);        // light q-tile  -> uniform 34 KV-tiles per block
}

// ---------------------------------------------------------------------------
extern "C" void kernel_launch(void* const* d_in, const int* in_sizes, int n_in,
                              void* d_out, int out_size, void* d_ws, size_t ws_size,
                              hipStream_t stream) {
  const float* x      = (const float*)d_in[0];   // [4,2048,1024]
  const float* w_qkv  = (const float*)d_in[1];   // [1024,3072]
  const float* w_proj = (const float*)d_in[2];   // [1024,1024]
  float* out = (float*)d_out;                    // [4,2048,1024] f32
  char* ws = (char*)d_ws;
  const size_t MB = 1024 * 1024;
  // xb and ao alias (ao written by attn after gemm1 consumed xb).
  unsigned short* xb     = (unsigned short*)(ws);            // 16MB [8192][1024]
  unsigned short* ao     = (unsigned short*)(ws);            // 16MB [8192][1024]
  unsigned short* wqkvT  = (unsigned short*)(ws + 16 * MB);  // 6MB [3072][1024]
  unsigned short* wprojT = (unsigned short*)(ws + 22 * MB);  // 2MB [1024][1024]
  unsigned short* q      = (unsigned short*)(ws + 24 * MB);  // 16MB [64][2048][64]
  unsigned short* k      = (unsigned short*)(ws + 40 * MB);  // 16MB
  unsigned short* vT     = (unsigned short*)(ws + 56 * MB);  // 16MB [64][64][2048]

  k_cast_bf16<<<4096, 256, 0, stream>>>(x, xb, 1048576);
  k_transpose_w<<<dim3(48, 16), 256, 0, stream>>>(w_qkv, wqkvT, 1024, 3072);
  k_transpose_w<<<dim3(16, 16), 256, 0, stream>>>(w_proj, wprojT, 1024, 1024);
  const float qscale = 0.125f * 1.44269504088896f;  // hd^-0.5 * log2(e)
  k_gemm<0><<<1536, 256, 0, stream>>>(xb, wqkvT, 8192, 3072, 1024,
                                      nullptr, q, k, vT, qscale);
  k_attn<<<512, 512, 0, stream>>>(q, k, vT, ao);
  k_gemm<1><<<512, 256, 0, stream>>>(ao, wprojT, 8192, 1024, 1024,
                                     out, nullptr, nullptr, nullptr, 1.f);
}